// Round 7
// baseline (749.217 us; speedup 1.0000x reference)
//
#include <hip/hip_runtime.h>

// ---------------------------------------------------------------------------
// mLSTM block, MI355X. B=2,S=2048,D=1024,NH=8,DH=128.
// v6: exact scalar-fp32 PV (v3 numerics, conflict-free interleaved channels),
//     128^2 GEMMs, complementary qt pairing, K-stride 148, prefetch.
// ---------------------------------------------------------------------------

typedef __bf16 bf16x8 __attribute__((ext_vector_type(8)));
typedef float f32x4 __attribute__((ext_vector_type(4)));
typedef unsigned short us8 __attribute__((ext_vector_type(8)));
typedef unsigned short us4 __attribute__((ext_vector_type(4)));

__device__ __forceinline__ unsigned short f2bf(float f) {
    unsigned int u = __builtin_bit_cast(unsigned int, f);
    unsigned int r = u + 0x7fffu + ((u >> 16) & 1u);
    return (unsigned short)(r >> 16);
}
__device__ __forceinline__ float bf2f(unsigned short h) {
    unsigned int u = ((unsigned int)h) << 16;
    return __builtin_bit_cast(float, u);
}
__device__ __forceinline__ f32x4 mfma16(bf16x8 a, bf16x8 b, f32x4 c) {
    return __builtin_amdgcn_mfma_f32_16x16x32_bf16(a, b, c, 0, 0, 0);
}

// ---------------- K0 ----------------
__global__ __launch_bounds__(256) void k_split_bf16(const float* __restrict__ in,
                                                    unsigned short* __restrict__ hi,
                                                    unsigned short* __restrict__ lo, int n) {
    int i = blockIdx.x * 256 + threadIdx.x;
    if (i < n) {
        float f = in[i];
        unsigned short h = f2bf(f);
        hi[i] = h;
        lo[i] = f2bf(f - bf2f(h));
    }
}

__global__ __launch_bounds__(256) void build_wcat(const float* __restrict__ Wq,
                                                  const float* __restrict__ Wk,
                                                  const float* __restrict__ Wv,
                                                  const float* __restrict__ Wog,
                                                  unsigned short* __restrict__ wh,
                                                  unsigned short* __restrict__ wl) {
    int idx = blockIdx.x * 256 + threadIdx.x;
    if (idx >= 2304 * 1024) return;
    int row = idx >> 10, col = idx & 1023;
    float v;
    if (row < 1024)      v = Wq[(size_t)row * 1024 + col] * 0.08838834764831845f;
    else if (row < 1152) v = Wk[(size_t)(row - 1024) * 1024 + col];
    else if (row < 1280) v = Wv[(size_t)(row - 1152) * 1024 + col];
    else                 v = Wog[(size_t)(row - 1280) * 1024 + col];
    unsigned short h = f2bf(v);
    wh[idx] = h;
    wl[idx] = f2bf(v - bf2f(h));
}

// ---------------- K1: gates ----------------
__global__ __launch_bounds__(256) void gates_kernel(const float* __restrict__ x,
                                                    const float* __restrict__ Wi,
                                                    const float* __restrict__ bi,
                                                    const float* __restrict__ Wf,
                                                    const float* __restrict__ bfb,
                                                    float* __restrict__ ipre,
                                                    float* __restrict__ lgf) {
    int bs = blockIdx.x;
    int b = bs >> 11, s = bs & 2047;
    const float* xr = x + (size_t)bs * 1024;
    int lane = threadIdx.x & 63, w = threadIdx.x >> 6;
    const float* W = (w < 2) ? Wi : Wf;
    int h0 = (w & 1) * 4;
    float dot0 = 0.f, dot1 = 0.f, dot2 = 0.f, dot3 = 0.f;
    for (int i = lane; i < 1024; i += 64) {
        float xv = xr[i];
        dot0 += xv * W[(size_t)(h0 + 0) * 1024 + i];
        dot1 += xv * W[(size_t)(h0 + 1) * 1024 + i];
        dot2 += xv * W[(size_t)(h0 + 2) * 1024 + i];
        dot3 += xv * W[(size_t)(h0 + 3) * 1024 + i];
    }
#pragma unroll
    for (int o = 32; o; o >>= 1) {
        dot0 += __shfl_xor(dot0, o);
        dot1 += __shfl_xor(dot1, o);
        dot2 += __shfl_xor(dot2, o);
        dot3 += __shfl_xor(dot3, o);
    }
    if (lane == 0) {
        float d[4] = {dot0, dot1, dot2, dot3};
#pragma unroll
        for (int j = 0; j < 4; j++) {
            int hh = h0 + j;
            if (w < 2) {
                float z = d[j] + bi[hh];
                z = 15.f * tanhf(z * (1.f / 15.f));
                ipre[((size_t)b * 8 + hh) * 2048 + s] = z;
            } else {
                float z = d[j] + bfb[hh];
                z = 15.f * tanhf(z * (1.f / 15.f));
                lgf[((size_t)b * 8 + hh) * 2048 + s] = fminf(z, 0.f) - log1pf(expf(-fabsf(z)));
            }
        }
    }
}

// ---------------- K2: scan ----------------
__global__ void scan_kernel(const float* __restrict__ ipre, const float* __restrict__ lgf,
                            float* __restrict__ csum, float* __restrict__ aarr,
                            float* __restrict__ marr) {
    int bh = blockIdx.x;
    int lane = threadIdx.x;
    const float* lf = lgf + (size_t)bh * 2048;
    const float* ip = ipre + (size_t)bh * 2048;
    float* cs = csum + (size_t)bh * 2048;
    float* aa = aarr + (size_t)bh * 2048;
    float* mm = marr + (size_t)bh * 2048;
    float carry = 0.f;
    float carrym = -1e30f;
    for (int c = 0; c < 32; c++) {
        float v = lf[c * 64 + lane];
#pragma unroll
        for (int o = 1; o < 64; o <<= 1) {
            float t = __shfl_up(v, o);
            if (lane >= o) v += t;
        }
        float cval = carry + v;
        cs[c * 64 + lane] = cval;
        float a = ip[c * 64 + lane] - cval;
        aa[c * 64 + lane] = a;
        float mv = a;
#pragma unroll
        for (int o = 1; o < 64; o <<= 1) {
            float t = __shfl_up(mv, o);
            if (lane >= o) mv = fmaxf(mv, t);
        }
        float mval = fmaxf(carrym, mv);
        mm[c * 64 + lane] = mval;
        carry = __shfl(cval, 63);
        carrym = __shfl(mval, 63);
    }
}

// ---- K3/K6: 3-product GEMM, 128x128 tile.  C = (Ah+Al)(Bh+Bl)^T ----
__global__ __launch_bounds__(256) void gemm_bt3(const unsigned short* __restrict__ Ah,
                                                const unsigned short* __restrict__ Al,
                                                const unsigned short* __restrict__ Bh,
                                                const unsigned short* __restrict__ Bl,
                                                void* __restrict__ Cp,
                                                unsigned short* __restrict__ Clo,
                                                int K, int ldc, int c_bf16) {
    __shared__ __attribute__((aligned(16))) unsigned short Ash[128 * 40];
    __shared__ __attribute__((aligned(16))) unsigned short Asl[128 * 40];
    __shared__ __attribute__((aligned(16))) unsigned short Bsh[128 * 40];
    __shared__ __attribute__((aligned(16))) unsigned short Bsl[128 * 40];
    const int tid = threadIdx.x;
    const int lane = tid & 63, wv = tid >> 6;
    const int wr = wv >> 1, wc = wv & 1;
    const int fr = lane & 15, fg = lane >> 4;
    const int srow = tid >> 1, scol = (tid & 1) * 16;
    const size_t aoff = (size_t)(blockIdx.x * 128 + srow) * K + scol;
    const size_t boff = (size_t)(blockIdx.y * 128 + srow) * K + scol;
    f32x4 acc[4][4] = {};
    for (int kt = 0; kt < K; kt += 32) {
        us8 avh0 = *(const us8*)(Ah + aoff + kt);
        us8 avh1 = *(const us8*)(Ah + aoff + kt + 8);
        us8 avl0 = *(const us8*)(Al + aoff + kt);
        us8 avl1 = *(const us8*)(Al + aoff + kt + 8);
        us8 bvh0 = *(const us8*)(Bh + boff + kt);
        us8 bvh1 = *(const us8*)(Bh + boff + kt + 8);
        us8 bvl0 = *(const us8*)(Bl + boff + kt);
        us8 bvl1 = *(const us8*)(Bl + boff + kt + 8);
        __syncthreads();
        *(us8*)&Ash[srow * 40 + scol] = avh0;
        *(us8*)&Ash[srow * 40 + scol + 8] = avh1;
        *(us8*)&Asl[srow * 40 + scol] = avl0;
        *(us8*)&Asl[srow * 40 + scol + 8] = avl1;
        *(us8*)&Bsh[srow * 40 + scol] = bvh0;
        *(us8*)&Bsh[srow * 40 + scol + 8] = bvh1;
        *(us8*)&Bsl[srow * 40 + scol] = bvl0;
        *(us8*)&Bsl[srow * 40 + scol + 8] = bvl1;
        __syncthreads();
        bf16x8 bfh[4], bfl[4];
#pragma unroll
        for (int j = 0; j < 4; j++) {
            bfh[j] = __builtin_bit_cast(bf16x8, *(const us8*)&Bsh[(64 * wc + 16 * j + fr) * 40 + fg * 8]);
            bfl[j] = __builtin_bit_cast(bf16x8, *(const us8*)&Bsl[(64 * wc + 16 * j + fr) * 40 + fg * 8]);
        }
        __builtin_amdgcn_s_setprio(1);
#pragma unroll
        for (int i = 0; i < 4; i++) {
            bf16x8 afh = __builtin_bit_cast(bf16x8, *(const us8*)&Ash[(64 * wr + 16 * i + fr) * 40 + fg * 8]);
            bf16x8 afl = __builtin_bit_cast(bf16x8, *(const us8*)&Asl[(64 * wr + 16 * i + fr) * 40 + fg * 8]);
#pragma unroll
            for (int j = 0; j < 4; j++) {
                acc[i][j] = mfma16(afh, bfh[j], acc[i][j]);
                acc[i][j] = mfma16(afh, bfl[j], acc[i][j]);
                acc[i][j] = mfma16(afl, bfh[j], acc[i][j]);
            }
        }
        __builtin_amdgcn_s_setprio(0);
    }
#pragma unroll
    for (int i = 0; i < 4; i++)
#pragma unroll
        for (int j = 0; j < 4; j++)
#pragma unroll
            for (int e = 0; e < 4; e++) {
                int r = blockIdx.x * 128 + 64 * wr + 16 * i + fg * 4 + e;
                int c = blockIdx.y * 128 + 64 * wc + 16 * j + fr;
                float v = acc[i][j][e];
                if (c_bf16) {
                    unsigned short h = f2bf(v);
                    ((unsigned short*)Cp)[(size_t)r * ldc + c] = h;
                    Clo[(size_t)r * ldc + c] = f2bf(v - bf2f(h));
                } else {
                    ((float*)Cp)[(size_t)r * ldc + c] = v;
                }
            }
}

// ---------------- K5: fused attn, MFMA QK + scalar-fp32 PV ----------------
__global__ __launch_bounds__(256) void attn_fused(const unsigned short* __restrict__ projh,
                                                  const unsigned short* __restrict__ projl,
                                                  const float* __restrict__ aarr,
                                                  const float* __restrict__ marr,
                                                  const float* __restrict__ csum,
                                                  const float* __restrict__ lnw,
                                                  unsigned short* __restrict__ hout,
                                                  unsigned short* __restrict__ hout_lo) {
    __shared__ __attribute__((aligned(16))) unsigned short Klh[32 * 148];
    __shared__ __attribute__((aligned(16))) unsigned short Kll[32 * 148];
    __shared__ __attribute__((aligned(16))) float Vf[32 * 132];
    __shared__ __attribute__((aligned(16))) float Pf[4][16 * 36];
    __shared__ float al[32];

    // complementary pairing: blocks i and i+256 -> (bh,qt) and (bh,31-qt)
    const int idx = blockIdx.x;           // 0..511
    const int half = idx >> 8;
    const int pid = idx & 255;
    const int bh = pid & 15;
    const int qt0 = pid >> 4;
    const int qt = half ? (31 - qt0) : qt0;
    const int b = bh >> 3, h = bh & 7;
    const int tid = threadIdx.x, lane = tid & 63, w = tid >> 6;
    const int fr = lane & 15, fg = lane >> 4;
    const int q0 = qt * 64;

    // ---- QK-phase per-lane state ----
    bf16x8 qfh[4], qfl[4];
    {
        const size_t qoff = (size_t)(b * 2048 + q0 + 16 * w + fr) * 2304 + h * 128;
#pragma unroll
        for (int ks = 0; ks < 4; ks++) {
            qfh[ks] = __builtin_bit_cast(bf16x8, *(const us8*)(projh + qoff + ks * 32 + fg * 8));
            qfl[ks] = __builtin_bit_cast(bf16x8, *(const us8*)(projl + qoff + ks * 32 + fg * 8));
        }
    }
    float maqk[4];
#pragma unroll
    for (int r = 0; r < 4; r++)
        maqk[r] = marr[(size_t)bh * 2048 + q0 + 16 * w + fg * 4 + r];

    // ---- PV-phase per-lane state (interleaved channels: c = 16*m + 4*j) ----
    const int rpv = lane >> 2;            // q-row within wave tile
    const int j4 = (lane & 3) * 4;        // channel sub-offset
    const int sgpv = q0 + 16 * w + rpv;
    const float cs_pv = csum[(size_t)bh * 2048 + sgpv];
    const float ma_pv = marr[(size_t)bh * 2048 + sgpv];
    f32x4 accs[8] = {};
    float b_run = 0.f;

    // staging ids
    const int kr = tid >> 3, kc = (tid & 7) * 16;
    const int vrow = tid >> 3, vcol = (tid & 7) * 16;
    const size_t kbase = (size_t)(b * 2048) * 2304 + 1024;
    const size_t vgbase = (size_t)(b * 2048) * 2304 + 1152;

    const int nt = 2 * qt + 2;
    us8 kh0, kh1, kl0, kl1, vh0, vh1, vl0, vl1;
    float a_st;
#define LOADT(T0)                                                              \
    {                                                                          \
        const size_t ko = kbase + (size_t)((T0) + kr) * 2304 + kc;             \
        const size_t vo = vgbase + (size_t)((T0) + vrow) * 2304 + vcol;        \
        kh0 = *(const us8*)(projh + ko);                                       \
        kh1 = *(const us8*)(projh + ko + 8);                                   \
        kl0 = *(const us8*)(projl + ko);                                       \
        kl1 = *(const us8*)(projl + ko + 8);                                   \
        vh0 = *(const us8*)(projh + vo);                                       \
        vh1 = *(const us8*)(projh + vo + 8);                                   \
        vl0 = *(const us8*)(projl + vo);                                       \
        vl1 = *(const us8*)(projl + vo + 8);                                   \
        a_st = (tid < 32) ? aarr[(size_t)bh * 2048 + (T0) + tid] : 0.f;        \
    }

    LOADT(0);
    for (int kt = 0; kt < nt; kt++) {
        const int t0 = kt * 32;
        __syncthreads();
        *(us8*)&Klh[kr * 148 + kc] = kh0;
        *(us8*)&Klh[kr * 148 + kc + 8] = kh1;
        *(us8*)&Kll[kr * 148 + kc] = kl0;
        *(us8*)&Kll[kr * 148 + kc + 8] = kl1;
        {
            f32x4 vv0, vv1, vv2, vv3;
#pragma unroll
            for (int e = 0; e < 4; e++) {
                vv0[e] = bf2f(vh0[e]) + bf2f(vl0[e]);
                vv1[e] = bf2f(vh0[4 + e]) + bf2f(vl0[4 + e]);
                vv2[e] = bf2f(vh1[e]) + bf2f(vl1[e]);
                vv3[e] = bf2f(vh1[4 + e]) + bf2f(vl1[4 + e]);
            }
            float* vd = &Vf[vrow * 132 + vcol];
            *(f32x4*)(vd + 0) = vv0;
            *(f32x4*)(vd + 4) = vv1;
            *(f32x4*)(vd + 8) = vv2;
            *(f32x4*)(vd + 12) = vv3;
        }
        if (tid < 32) al[tid] = a_st;
        __syncthreads();
        if (kt + 1 < nt) LOADT(t0 + 32);

        // QK^T 3-product MFMA; P final-valued via exact prefix-max; f32 LDS
#pragma unroll
        for (int j = 0; j < 2; j++) {
            f32x4 sf = {};
            __builtin_amdgcn_s_setprio(1);
#pragma unroll
            for (int ks = 0; ks < 4; ks++) {
                bf16x8 kfh = __builtin_bit_cast(bf16x8, *(const us8*)&Klh[(j * 16 + fr) * 148 + ks * 32 + fg * 8]);
                bf16x8 kfl = __builtin_bit_cast(bf16x8, *(const us8*)&Kll[(j * 16 + fr) * 148 + ks * 32 + fg * 8]);
                sf = mfma16(qfh[ks], kfh, sf);
                sf = mfma16(qfh[ks], kfl, sf);
                sf = mfma16(qfl[ks], kfh, sf);
            }
            __builtin_amdgcn_s_setprio(0);
            const float atj = al[j * 16 + fr];
            const int key = t0 + j * 16 + fr;
#pragma unroll
            for (int r = 0; r < 4; r++) {
                const int sg = q0 + 16 * w + fg * 4 + r;
                float p = (key <= sg) ? sf[r] * __expf(atj - maqk[r]) : 0.f;
                Pf[w][(fg * 4 + r) * 36 + j * 16 + fr] = p;
            }
        }
        __asm__ volatile("s_waitcnt lgkmcnt(0)" ::: "memory");
        __builtin_amdgcn_sched_barrier(0);

        // scalar-fp32 PV: row rpv, interleaved channel chunks 16*m + j4
        {
            const float* pr = &Pf[w][rpv * 36];
#pragma unroll 4
            for (int t = 0; t < 32; t++) {
                float p = pr[t];
                b_run += p;
                const float* vrow_p = &Vf[t * 132 + j4];
#pragma unroll
                for (int m = 0; m < 8; m++) {
                    f32x4 vv = *(const f32x4*)(vrow_p + m * 16);
                    accs[m] += p * vv;
                }
            }
        }
    }
#undef LOADT

    // finalize: n-divide, LayerNorm over 128 channels of row rpv, og gate
    const float nf = __expf(-(cs_pv + ma_pv));
    const float n = fmaxf(fabsf(b_run), nf);
    const float inv = 1.f / (n + 1e-6f);
#pragma unroll
    for (int m = 0; m < 8; m++) accs[m] *= inv;

    float s = 0.f;
#pragma unroll
    for (int m = 0; m < 8; m++) s += accs[m][0] + accs[m][1] + accs[m][2] + accs[m][3];
    s += __shfl_xor(s, 1);
    s += __shfl_xor(s, 2);
    const float mu = s * (1.f / 128.f);
    float vv = 0.f;
#pragma unroll
    for (int m = 0; m < 8; m++)
#pragma unroll
        for (int e = 0; e < 4; e++) {
            float d = accs[m][e] - mu;
            vv += d * d;
        }
    vv += __shfl_xor(vv, 1);
    vv += __shfl_xor(vv, 2);
    const float rstd = rsqrtf(vv * (1.f / 128.f) + 1e-6f);

    const size_t obase = (size_t)(b * 2048 + sgpv) * 2304 + 1280 + h * 128 + j4;
    const size_t hbase = (size_t)(b * 2048 + sgpv) * 1024 + h * 128 + j4;
#pragma unroll
    for (int m = 0; m < 8; m++) {
        us4 ogh = *(const us4*)(projh + obase + m * 16);
        us4 ogl = *(const us4*)(projl + obase + m * 16);
        us4 hi4, lo4;
#pragma unroll
        for (int e = 0; e < 4; e++) {
            const float av = accs[m][e];
            const float og = bf2f(ogh[e]) + bf2f(ogl[e]);
            const float sig = 1.f / (1.f + __expf(-og));
            const float hn = (av - mu) * rstd * lnw[h * 128 + j4 + m * 16 + e];
            const float ho = hn * sig;
            unsigned short h1 = f2bf(ho);
            hi4[e] = h1;
            lo4[e] = f2bf(ho - bf2f(h1));
        }
        *(us4*)&hout[hbase + m * 16] = hi4;
        *(us4*)&hout_lo[hbase + m * 16] = lo4;
    }
}

// ---------------------------------------------------------------------------
extern "C" void kernel_launch(void* const* d_in, const int* in_sizes, int n_in,
                              void* d_out, int out_size, void* d_ws, size_t ws_size,
                              hipStream_t stream) {
    (void)in_sizes; (void)n_in; (void)out_size; (void)ws_size;
    const float* x    = (const float*)d_in[0];
    const float* Wq   = (const float*)d_in[1];
    const float* Wk   = (const float*)d_in[2];
    const float* Wv   = (const float*)d_in[3];
    const float* Wog  = (const float*)d_in[4];
    const float* Wi   = (const float*)d_in[5];
    const float* bi   = (const float*)d_in[6];
    const float* Wf   = (const float*)d_in[7];
    const float* bfb  = (const float*)d_in[8];
    const float* lnw  = (const float*)d_in[9];
    const float* Wout = (const float*)d_in[10];

    char* p = (char*)d_ws;
    auto carve = [&](size_t bytes) -> char* {
        char* r = p;
        p += (bytes + 255) & ~(size_t)255;
        return r;
    };
    unsigned short* x_hi   = (unsigned short*)carve(4194304ull * 2);
    unsigned short* x_lo   = (unsigned short*)carve(4194304ull * 2);
    unsigned short* wc_hi  = (unsigned short*)carve(2359296ull * 2);
    unsigned short* wc_lo  = (unsigned short*)carve(2359296ull * 2);
    unsigned short* wo_hi  = (unsigned short*)carve(1048576ull * 2);
    unsigned short* wo_lo  = (unsigned short*)carve(1048576ull * 2);
    unsigned short* pr_hi  = (unsigned short*)carve(4096ull * 2304 * 2);
    unsigned short* pr_lo  = (unsigned short*)carve(4096ull * 2304 * 2);
    float* ipre    = (float*)carve(32768ull * 4);
    float* lgf_buf = (float*)carve(32768ull * 4);
    float* csum    = (float*)carve(32768ull * 4);
    float* aarr    = (float*)carve(32768ull * 4);
    float* marr    = (float*)carve(32768ull * 4);
    unsigned short* ho_hi = x_hi;
    unsigned short* ho_lo = x_lo;

    k_split_bf16<<<16384, 256, 0, stream>>>(x, x_hi, x_lo, 4194304);
    build_wcat<<<(2359296 + 255) / 256, 256, 0, stream>>>(Wq, Wk, Wv, Wog, wc_hi, wc_lo);
    k_split_bf16<<<4096, 256, 0, stream>>>(Wout, wo_hi, wo_lo, 1048576);
    gates_kernel<<<4096, 256, 0, stream>>>(x, Wi, bi, Wf, bfb, ipre, lgf_buf);
    scan_kernel<<<16, 64, 0, stream>>>(ipre, lgf_buf, csum, aarr, marr);
    gemm_bt3<<<dim3(32, 18), 256, 0, stream>>>(x_hi, x_lo, wc_hi, wc_lo, pr_hi, pr_lo, 1024, 2304, 1);
    attn_fused<<<512, 256, 0, stream>>>(pr_hi, pr_lo, aarr, marr, csum, lnw, ho_hi, ho_lo);
    gemm_bt3<<<dim3(32, 8), 256, 0, stream>>>(ho_hi, ho_lo, wo_hi, wo_lo, d_out, nullptr, 1024, 1024, 0);
}

// Round 8
// 542.879 us; speedup vs baseline: 1.3801x; 1.3801x over previous
//
#include <hip/hip_runtime.h>

// ---------------------------------------------------------------------------
// mLSTM block, MI355X. B=2,S=2048,D=1024,NH=8,DH=128.
// v7: channel-split attn blocks (1024 blocks, 4/CU), exact scalar-fp32 PV,
//     LN+gate split into separate memory-bound kernel. v6 numerics (+~1e-4).
// ---------------------------------------------------------------------------

typedef __bf16 bf16x8 __attribute__((ext_vector_type(8)));
typedef float f32x4 __attribute__((ext_vector_type(4)));
typedef float f32x2 __attribute__((ext_vector_type(2)));
typedef unsigned short us8 __attribute__((ext_vector_type(8)));
typedef unsigned short us4 __attribute__((ext_vector_type(4)));
typedef unsigned short us2 __attribute__((ext_vector_type(2)));

__device__ __forceinline__ unsigned short f2bf(float f) {
    unsigned int u = __builtin_bit_cast(unsigned int, f);
    unsigned int r = u + 0x7fffu + ((u >> 16) & 1u);
    return (unsigned short)(r >> 16);
}
__device__ __forceinline__ float bf2f(unsigned short h) {
    unsigned int u = ((unsigned int)h) << 16;
    return __builtin_bit_cast(float, u);
}
__device__ __forceinline__ f32x4 mfma16(bf16x8 a, bf16x8 b, f32x4 c) {
    return __builtin_amdgcn_mfma_f32_16x16x32_bf16(a, b, c, 0, 0, 0);
}

// ---------------- K0 ----------------
__global__ __launch_bounds__(256) void k_split_bf16(const float* __restrict__ in,
                                                    unsigned short* __restrict__ hi,
                                                    unsigned short* __restrict__ lo, int n) {
    int i = blockIdx.x * 256 + threadIdx.x;
    if (i < n) {
        float f = in[i];
        unsigned short h = f2bf(f);
        hi[i] = h;
        lo[i] = f2bf(f - bf2f(h));
    }
}

__global__ __launch_bounds__(256) void build_wcat(const float* __restrict__ Wq,
                                                  const float* __restrict__ Wk,
                                                  const float* __restrict__ Wv,
                                                  const float* __restrict__ Wog,
                                                  unsigned short* __restrict__ wh,
                                                  unsigned short* __restrict__ wl) {
    int idx = blockIdx.x * 256 + threadIdx.x;
    if (idx >= 2304 * 1024) return;
    int row = idx >> 10, col = idx & 1023;
    float v;
    if (row < 1024)      v = Wq[(size_t)row * 1024 + col] * 0.08838834764831845f;
    else if (row < 1152) v = Wk[(size_t)(row - 1024) * 1024 + col];
    else if (row < 1280) v = Wv[(size_t)(row - 1152) * 1024 + col];
    else                 v = Wog[(size_t)(row - 1280) * 1024 + col];
    unsigned short h = f2bf(v);
    wh[idx] = h;
    wl[idx] = f2bf(v - bf2f(h));
}

// ---------------- K1: gates ----------------
__global__ __launch_bounds__(256) void gates_kernel(const float* __restrict__ x,
                                                    const float* __restrict__ Wi,
                                                    const float* __restrict__ bi,
                                                    const float* __restrict__ Wf,
                                                    const float* __restrict__ bfb,
                                                    float* __restrict__ ipre,
                                                    float* __restrict__ lgf) {
    int bs = blockIdx.x;
    int b = bs >> 11, s = bs & 2047;
    const float* xr = x + (size_t)bs * 1024;
    int lane = threadIdx.x & 63, w = threadIdx.x >> 6;
    const float* W = (w < 2) ? Wi : Wf;
    int h0 = (w & 1) * 4;
    float dot0 = 0.f, dot1 = 0.f, dot2 = 0.f, dot3 = 0.f;
    for (int i = lane; i < 1024; i += 64) {
        float xv = xr[i];
        dot0 += xv * W[(size_t)(h0 + 0) * 1024 + i];
        dot1 += xv * W[(size_t)(h0 + 1) * 1024 + i];
        dot2 += xv * W[(size_t)(h0 + 2) * 1024 + i];
        dot3 += xv * W[(size_t)(h0 + 3) * 1024 + i];
    }
#pragma unroll
    for (int o = 32; o; o >>= 1) {
        dot0 += __shfl_xor(dot0, o);
        dot1 += __shfl_xor(dot1, o);
        dot2 += __shfl_xor(dot2, o);
        dot3 += __shfl_xor(dot3, o);
    }
    if (lane == 0) {
        float d[4] = {dot0, dot1, dot2, dot3};
#pragma unroll
        for (int j = 0; j < 4; j++) {
            int hh = h0 + j;
            if (w < 2) {
                float z = d[j] + bi[hh];
                z = 15.f * tanhf(z * (1.f / 15.f));
                ipre[((size_t)b * 8 + hh) * 2048 + s] = z;
            } else {
                float z = d[j] + bfb[hh];
                z = 15.f * tanhf(z * (1.f / 15.f));
                lgf[((size_t)b * 8 + hh) * 2048 + s] = fminf(z, 0.f) - log1pf(expf(-fabsf(z)));
            }
        }
    }
}

// ---------------- K2: scan ----------------
__global__ void scan_kernel(const float* __restrict__ ipre, const float* __restrict__ lgf,
                            float* __restrict__ csum, float* __restrict__ aarr,
                            float* __restrict__ marr) {
    int bh = blockIdx.x;
    int lane = threadIdx.x;
    const float* lf = lgf + (size_t)bh * 2048;
    const float* ip = ipre + (size_t)bh * 2048;
    float* cs = csum + (size_t)bh * 2048;
    float* aa = aarr + (size_t)bh * 2048;
    float* mm = marr + (size_t)bh * 2048;
    float carry = 0.f;
    float carrym = -1e30f;
    for (int c = 0; c < 32; c++) {
        float v = lf[c * 64 + lane];
#pragma unroll
        for (int o = 1; o < 64; o <<= 1) {
            float t = __shfl_up(v, o);
            if (lane >= o) v += t;
        }
        float cval = carry + v;
        cs[c * 64 + lane] = cval;
        float a = ip[c * 64 + lane] - cval;
        aa[c * 64 + lane] = a;
        float mv = a;
#pragma unroll
        for (int o = 1; o < 64; o <<= 1) {
            float t = __shfl_up(mv, o);
            if (lane >= o) mv = fmaxf(mv, t);
        }
        float mval = fmaxf(carrym, mv);
        mm[c * 64 + lane] = mval;
        carry = __shfl(cval, 63);
        carrym = __shfl(mval, 63);
    }
}

// ---- K3/K6: 3-product GEMM, 128x128 tile ----
__global__ __launch_bounds__(256) void gemm_bt3(const unsigned short* __restrict__ Ah,
                                                const unsigned short* __restrict__ Al,
                                                const unsigned short* __restrict__ Bh,
                                                const unsigned short* __restrict__ Bl,
                                                void* __restrict__ Cp,
                                                unsigned short* __restrict__ Clo,
                                                int K, int ldc, int c_bf16) {
    __shared__ __attribute__((aligned(16))) unsigned short Ash[128 * 40];
    __shared__ __attribute__((aligned(16))) unsigned short Asl[128 * 40];
    __shared__ __attribute__((aligned(16))) unsigned short Bsh[128 * 40];
    __shared__ __attribute__((aligned(16))) unsigned short Bsl[128 * 40];
    const int tid = threadIdx.x;
    const int lane = tid & 63, wv = tid >> 6;
    const int wr = wv >> 1, wc = wv & 1;
    const int fr = lane & 15, fg = lane >> 4;
    const int srow = tid >> 1, scol = (tid & 1) * 16;
    const size_t aoff = (size_t)(blockIdx.x * 128 + srow) * K + scol;
    const size_t boff = (size_t)(blockIdx.y * 128 + srow) * K + scol;
    f32x4 acc[4][4] = {};
    for (int kt = 0; kt < K; kt += 32) {
        us8 avh0 = *(const us8*)(Ah + aoff + kt);
        us8 avh1 = *(const us8*)(Ah + aoff + kt + 8);
        us8 avl0 = *(const us8*)(Al + aoff + kt);
        us8 avl1 = *(const us8*)(Al + aoff + kt + 8);
        us8 bvh0 = *(const us8*)(Bh + boff + kt);
        us8 bvh1 = *(const us8*)(Bh + boff + kt + 8);
        us8 bvl0 = *(const us8*)(Bl + boff + kt);
        us8 bvl1 = *(const us8*)(Bl + boff + kt + 8);
        __syncthreads();
        *(us8*)&Ash[srow * 40 + scol] = avh0;
        *(us8*)&Ash[srow * 40 + scol + 8] = avh1;
        *(us8*)&Asl[srow * 40 + scol] = avl0;
        *(us8*)&Asl[srow * 40 + scol + 8] = avl1;
        *(us8*)&Bsh[srow * 40 + scol] = bvh0;
        *(us8*)&Bsh[srow * 40 + scol + 8] = bvh1;
        *(us8*)&Bsl[srow * 40 + scol] = bvl0;
        *(us8*)&Bsl[srow * 40 + scol + 8] = bvl1;
        __syncthreads();
        bf16x8 bfh[4], bfl[4];
#pragma unroll
        for (int j = 0; j < 4; j++) {
            bfh[j] = __builtin_bit_cast(bf16x8, *(const us8*)&Bsh[(64 * wc + 16 * j + fr) * 40 + fg * 8]);
            bfl[j] = __builtin_bit_cast(bf16x8, *(const us8*)&Bsl[(64 * wc + 16 * j + fr) * 40 + fg * 8]);
        }
        __builtin_amdgcn_s_setprio(1);
#pragma unroll
        for (int i = 0; i < 4; i++) {
            bf16x8 afh = __builtin_bit_cast(bf16x8, *(const us8*)&Ash[(64 * wr + 16 * i + fr) * 40 + fg * 8]);
            bf16x8 afl = __builtin_bit_cast(bf16x8, *(const us8*)&Asl[(64 * wr + 16 * i + fr) * 40 + fg * 8]);
#pragma unroll
            for (int j = 0; j < 4; j++) {
                acc[i][j] = mfma16(afh, bfh[j], acc[i][j]);
                acc[i][j] = mfma16(afh, bfl[j], acc[i][j]);
                acc[i][j] = mfma16(afl, bfh[j], acc[i][j]);
            }
        }
        __builtin_amdgcn_s_setprio(0);
    }
#pragma unroll
    for (int i = 0; i < 4; i++)
#pragma unroll
        for (int j = 0; j < 4; j++)
#pragma unroll
            for (int e = 0; e < 4; e++) {
                int r = blockIdx.x * 128 + 64 * wr + 16 * i + fg * 4 + e;
                int c = blockIdx.y * 128 + 64 * wc + 16 * j + fr;
                float v = acc[i][j][e];
                if (c_bf16) {
                    unsigned short h = f2bf(v);
                    ((unsigned short*)Cp)[(size_t)r * ldc + c] = h;
                    Clo[(size_t)r * ldc + c] = f2bf(v - bf2f(h));
                } else {
                    ((float*)Cp)[(size_t)r * ldc + c] = v;
                }
            }
}

// ---------------- K5: fused attn, channel-split, scalar-fp32 PV ----------------
__global__ __launch_bounds__(256) void attn_fused(const unsigned short* __restrict__ projh,
                                                  const unsigned short* __restrict__ projl,
                                                  const float* __restrict__ aarr,
                                                  const float* __restrict__ marr,
                                                  const float* __restrict__ csum,
                                                  unsigned short* __restrict__ ho_hi,
                                                  unsigned short* __restrict__ ho_lo,
                                                  float* __restrict__ psum) {
    __shared__ __attribute__((aligned(16))) unsigned short Klh[32 * 148];
    __shared__ __attribute__((aligned(16))) unsigned short Kll[32 * 148];
    __shared__ __attribute__((aligned(16))) float Vf[32 * 68];
    __shared__ __attribute__((aligned(16))) float Pf[4][16 * 36];
    __shared__ float al[32];

    // 1024 blocks = (bh, qt, ch-half); (i, i+512) complementary for balance
    const int idx = blockIdx.x;
    const int chh = idx >> 9;
    const int bh = idx & 15;
    int qt = (idx >> 4) & 31;
    if (chh) qt = 31 - qt;
    const int b = bh >> 3, h = bh & 7;
    const int tid = threadIdx.x, lane = tid & 63, w = tid >> 6;
    const int fr = lane & 15, fg = lane >> 4;
    const int q0 = qt * 64;

    // ---- QK-phase per-lane state ----
    bf16x8 qfh[4], qfl[4];
    {
        const size_t qoff = (size_t)(b * 2048 + q0 + 16 * w + fr) * 2304 + h * 128;
#pragma unroll
        for (int ks = 0; ks < 4; ks++) {
            qfh[ks] = __builtin_bit_cast(bf16x8, *(const us8*)(projh + qoff + ks * 32 + fg * 8));
            qfl[ks] = __builtin_bit_cast(bf16x8, *(const us8*)(projl + qoff + ks * 32 + fg * 8));
        }
    }
    float maqk[4];
#pragma unroll
    for (int r = 0; r < 4; r++)
        maqk[r] = marr[(size_t)bh * 2048 + q0 + 16 * w + fg * 4 + r];

    // ---- PV-phase per-lane state: 16 channels = chh*64 + 16m + j4 + e ----
    const int rpv = lane >> 2;
    const int j4 = (lane & 3) * 4;
    const int sgpv = q0 + 16 * w + rpv;
    const float cs_pv = csum[(size_t)bh * 2048 + sgpv];
    const float ma_pv = marr[(size_t)bh * 2048 + sgpv];
    f32x4 accs[4] = {};
    float b_run = 0.f;

    // staging ids
    const int kr = tid >> 3, kc = (tid & 7) * 16;
    const int vrow = tid >> 3, vch8 = (tid & 7) * 8;
    const size_t kbase = (size_t)(b * 2048) * 2304 + 1024;
    const size_t vgbase = (size_t)(b * 2048) * 2304 + 1152 + chh * 64;

    const int nt = 2 * qt + 2;
    us8 kh0, kh1, kl0, kl1, vh0, vl0;
    float a_st;
#define LOADT(T0)                                                              \
    {                                                                          \
        const size_t ko = kbase + (size_t)((T0) + kr) * 2304 + kc;             \
        const size_t vo = vgbase + (size_t)((T0) + vrow) * 2304 + vch8;        \
        kh0 = *(const us8*)(projh + ko);                                       \
        kh1 = *(const us8*)(projh + ko + 8);                                   \
        kl0 = *(const us8*)(projl + ko);                                       \
        kl1 = *(const us8*)(projl + ko + 8);                                   \
        vh0 = *(const us8*)(projh + vo);                                       \
        vl0 = *(const us8*)(projl + vo);                                       \
        a_st = (tid < 32) ? aarr[(size_t)bh * 2048 + (T0) + tid] : 0.f;        \
    }

    LOADT(0);
    for (int kt = 0; kt < nt; kt++) {
        const int t0 = kt * 32;
        __syncthreads();
        *(us8*)&Klh[kr * 148 + kc] = kh0;
        *(us8*)&Klh[kr * 148 + kc + 8] = kh1;
        *(us8*)&Kll[kr * 148 + kc] = kl0;
        *(us8*)&Kll[kr * 148 + kc + 8] = kl1;
        {
            f32x4 vv0, vv1;
#pragma unroll
            for (int e = 0; e < 4; e++) {
                vv0[e] = bf2f(vh0[e]) + bf2f(vl0[e]);
                vv1[e] = bf2f(vh0[4 + e]) + bf2f(vl0[4 + e]);
            }
            float* vd = &Vf[vrow * 68 + vch8];
            *(f32x4*)(vd + 0) = vv0;
            *(f32x4*)(vd + 4) = vv1;
        }
        if (tid < 32) al[tid] = a_st;
        __syncthreads();
        if (kt + 1 < nt) LOADT(t0 + 32);

        // QK^T 3-product MFMA; P final-valued via exact prefix-max; f32 LDS
#pragma unroll
        for (int j = 0; j < 2; j++) {
            f32x4 sf = {};
            __builtin_amdgcn_s_setprio(1);
#pragma unroll
            for (int ks = 0; ks < 4; ks++) {
                bf16x8 kfh = __builtin_bit_cast(bf16x8, *(const us8*)&Klh[(j * 16 + fr) * 148 + ks * 32 + fg * 8]);
                bf16x8 kfl = __builtin_bit_cast(bf16x8, *(const us8*)&Kll[(j * 16 + fr) * 148 + ks * 32 + fg * 8]);
                sf = mfma16(qfh[ks], kfh, sf);
                sf = mfma16(qfh[ks], kfl, sf);
                sf = mfma16(qfl[ks], kfh, sf);
            }
            __builtin_amdgcn_s_setprio(0);
            const float atj = al[j * 16 + fr];
            const int key = t0 + j * 16 + fr;
#pragma unroll
            for (int r = 0; r < 4; r++) {
                const int sg = q0 + 16 * w + fg * 4 + r;
                float p = (key <= sg) ? sf[r] * __expf(atj - maqk[r]) : 0.f;
                Pf[w][(fg * 4 + r) * 36 + j * 16 + fr] = p;
            }
        }
        __asm__ volatile("s_waitcnt lgkmcnt(0)" ::: "memory");
        __builtin_amdgcn_sched_barrier(0);

        // scalar-fp32 PV: row rpv, 16 channels (4 chunks of 4)
        {
            const float* pr = &Pf[w][rpv * 36];
#pragma unroll 8
            for (int t = 0; t < 32; t++) {
                float p = pr[t];
                b_run += p;
                const float* vrow_p = &Vf[t * 68 + j4];
#pragma unroll
                for (int m = 0; m < 4; m++) {
                    f32x4 vv = *(const f32x4*)(vrow_p + m * 16);
                    accs[m] += p * vv;
                }
            }
        }
    }
#undef LOADT

    // finalize: n-divide, write h (hi/lo) + partial LN sums
    const float nf = __expf(-(cs_pv + ma_pv));
    const float n = fmaxf(fabsf(b_run), nf);
    const float inv = 1.f / (n + 1e-6f);
#pragma unroll
    for (int m = 0; m < 4; m++) accs[m] *= inv;

    float s1 = 0.f, s2 = 0.f;
#pragma unroll
    for (int m = 0; m < 4; m++)
#pragma unroll
        for (int e = 0; e < 4; e++) {
            float v = accs[m][e];
            s1 += v;
            s2 += v * v;
        }
    s1 += __shfl_xor(s1, 1);
    s1 += __shfl_xor(s1, 2);
    s2 += __shfl_xor(s2, 1);
    s2 += __shfl_xor(s2, 2);

    const size_t hbase = (size_t)(b * 2048 + sgpv) * 1024 + h * 128 + chh * 64 + j4;
#pragma unroll
    for (int m = 0; m < 4; m++) {
        us4 hi4, lo4;
#pragma unroll
        for (int e = 0; e < 4; e++) {
            float v = accs[m][e];
            unsigned short h1 = f2bf(v);
            hi4[e] = h1;
            lo4[e] = f2bf(v - bf2f(h1));
        }
        *(us4*)&ho_hi[hbase + m * 16] = hi4;
        *(us4*)&ho_lo[hbase + m * 16] = lo4;
    }
    if ((lane & 3) == 0) {
        const int rowid = bh * 2048 + sgpv;
        psum[(size_t)(chh * 2 + 0) * 32768 + rowid] = s1;
        psum[(size_t)(chh * 2 + 1) * 32768 + rowid] = s2;
    }
}

// ---------------- K5b: LayerNorm + og gate + re-split (in place) ----------------
__global__ __launch_bounds__(256) void ln_gate(unsigned short* __restrict__ ho_hi,
                                               unsigned short* __restrict__ ho_lo,
                                               const float* __restrict__ psum,
                                               const unsigned short* __restrict__ projh,
                                               const unsigned short* __restrict__ projl,
                                               const float* __restrict__ lnw) {
    const int row = blockIdx.x * 4 + (threadIdx.x >> 6);  // 0..32767 = (b,s,h)
    const int lane = threadIdx.x & 63;
    const int b = row >> 14;
    const int s = (row >> 3) & 2047;
    const int h = row & 7;
    const int rowid = (b * 8 + h) * 2048 + s;

    const float s1 = psum[rowid] + psum[2ull * 32768 + rowid];
    const float s2 = psum[1ull * 32768 + rowid] + psum[3ull * 32768 + rowid];
    const float mu = s1 * (1.f / 128.f);
    const float var = fmaxf(s2 * (1.f / 128.f) - mu * mu, 0.f);
    const float rstd = rsqrtf(var + 1e-6f);

    const int ch = lane * 2;
    const size_t hoff = (size_t)(row >> 3) * 1024 + h * 128 + ch;
    us2 hh = *(const us2*)&ho_hi[hoff];
    us2 hl = *(const us2*)&ho_lo[hoff];
    const float v0 = bf2f(hh[0]) + bf2f(hl[0]);
    const float v1 = bf2f(hh[1]) + bf2f(hl[1]);

    const size_t ogo = (size_t)(b * 2048 + s) * 2304 + 1280 + h * 128 + ch;
    us2 ogh = *(const us2*)&projh[ogo];
    us2 ogl = *(const us2*)&projl[ogo];
    const float og0 = bf2f(ogh[0]) + bf2f(ogl[0]);
    const float og1 = bf2f(ogh[1]) + bf2f(ogl[1]);
    const float sig0 = 1.f / (1.f + __expf(-og0));
    const float sig1 = 1.f / (1.f + __expf(-og1));

    f32x2 lw = *(const f32x2*)&lnw[h * 128 + ch];
    const float ho0 = (v0 - mu) * rstd * lw[0] * sig0;
    const float ho1 = (v1 - mu) * rstd * lw[1] * sig1;

    us2 oh, ol;
    unsigned short h0b = f2bf(ho0);
    unsigned short h1b = f2bf(ho1);
    oh[0] = h0b; oh[1] = h1b;
    ol[0] = f2bf(ho0 - bf2f(h0b));
    ol[1] = f2bf(ho1 - bf2f(h1b));
    *(us2*)&ho_hi[hoff] = oh;
    *(us2*)&ho_lo[hoff] = ol;
}

// ---------------------------------------------------------------------------
extern "C" void kernel_launch(void* const* d_in, const int* in_sizes, int n_in,
                              void* d_out, int out_size, void* d_ws, size_t ws_size,
                              hipStream_t stream) {
    (void)in_sizes; (void)n_in; (void)out_size; (void)ws_size;
    const float* x    = (const float*)d_in[0];
    const float* Wq   = (const float*)d_in[1];
    const float* Wk   = (const float*)d_in[2];
    const float* Wv   = (const float*)d_in[3];
    const float* Wog  = (const float*)d_in[4];
    const float* Wi   = (const float*)d_in[5];
    const float* bi   = (const float*)d_in[6];
    const float* Wf   = (const float*)d_in[7];
    const float* bfb  = (const float*)d_in[8];
    const float* lnw  = (const float*)d_in[9];
    const float* Wout = (const float*)d_in[10];

    char* p = (char*)d_ws;
    auto carve = [&](size_t bytes) -> char* {
        char* r = p;
        p += (bytes + 255) & ~(size_t)255;
        return r;
    };
    unsigned short* x_hi   = (unsigned short*)carve(4194304ull * 2);
    unsigned short* x_lo   = (unsigned short*)carve(4194304ull * 2);
    unsigned short* wc_hi  = (unsigned short*)carve(2359296ull * 2);
    unsigned short* wc_lo  = (unsigned short*)carve(2359296ull * 2);
    unsigned short* wo_hi  = (unsigned short*)carve(1048576ull * 2);
    unsigned short* wo_lo  = (unsigned short*)carve(1048576ull * 2);
    unsigned short* pr_hi  = (unsigned short*)carve(4096ull * 2304 * 2);
    unsigned short* pr_lo  = (unsigned short*)carve(4096ull * 2304 * 2);
    float* ipre    = (float*)carve(32768ull * 4);
    float* lgf_buf = (float*)carve(32768ull * 4);
    float* csum    = (float*)carve(32768ull * 4);
    float* aarr    = (float*)carve(32768ull * 4);
    float* marr    = (float*)carve(32768ull * 4);
    float* psum    = (float*)carve(4ull * 32768 * 4);
    unsigned short* ho_hi = x_hi;   // x dead after proj GEMM
    unsigned short* ho_lo = x_lo;

    k_split_bf16<<<16384, 256, 0, stream>>>(x, x_hi, x_lo, 4194304);
    build_wcat<<<(2359296 + 255) / 256, 256, 0, stream>>>(Wq, Wk, Wv, Wog, wc_hi, wc_lo);
    k_split_bf16<<<4096, 256, 0, stream>>>(Wout, wo_hi, wo_lo, 1048576);
    gates_kernel<<<4096, 256, 0, stream>>>(x, Wi, bi, Wf, bfb, ipre, lgf_buf);
    scan_kernel<<<16, 64, 0, stream>>>(ipre, lgf_buf, csum, aarr, marr);
    gemm_bt3<<<dim3(32, 18), 256, 0, stream>>>(x_hi, x_lo, wc_hi, wc_lo, pr_hi, pr_lo, 1024, 2304, 1);
    attn_fused<<<1024, 256, 0, stream>>>(pr_hi, pr_lo, aarr, marr, csum, ho_hi, ho_lo, psum);
    ln_gate<<<8192, 256, 0, stream>>>(ho_hi, ho_lo, psum, pr_hi, pr_lo, lnw);
    gemm_bt3<<<dim3(32, 8), 256, 0, stream>>>(ho_hi, ho_lo, wo_hi, wo_lo, d_out, nullptr, 1024, 1024, 0);
}